// Round 18
// baseline (126.673 us; speedup 1.0000x reference)
//
#include <hip/hip_runtime.h>
#include <stdint.h>

// 3-layer binary net. L0 fused in main. L1 = i8 MFMA with A in {0,1}, B in
// {+1,-1}: dot = 2s - popx directly, threshold = bare compare vs
// carr[o] = thr1[o] + popm[o] - 1024. L2 in a tiny separate kernel.
// R18: 4-deep B prefetch + 1-deep A prefetch (covers ~200cyc L2 latency).
// ws: cA 256K | cB 256K | M2p 3KB | carr 4KB | Bf 1MB (+-1 i8) | X2p 8MB
#define WS_CA   0
#define WS_CB   262144
#define WS_M2P  524288
#define WS_CARR 527360
#define WS_BF   532480
#define WS_X2   1581056

typedef int v4i  __attribute__((ext_vector_type(4)));
typedef int v16i __attribute__((ext_vector_type(16)));

// 16 bits -> 16 i8 bytes (0/1), byte e = bit e (LSB-first)
__device__ __forceinline__ v4i expand16(unsigned h) {
  v4i a;
  a.x = (int)(__umul24(h & 15u,         0x00204081u) & 0x01010101u);
  a.y = (int)(__umul24((h >> 4) & 15u,  0x00204081u) & 0x01010101u);
  a.z = (int)(__umul24((h >> 8) & 15u,  0x00204081u) & 0x01010101u);
  a.w = (int)(__umul24((h >> 12) & 15u, 0x00204081u) & 0x01010101u);
  return a;
}

// ---- mask upload-format sniffing (bool arrays may arrive as u8, i32, or f32) ----
__device__ inline int detect_mode(const unsigned char* p) {
  unsigned nonalign = 0;
  for (int i = 0; i < 64; i++)
    if (i & 3) nonalign |= p[i];
  if (nonalign == 0) return 1;                 // int32 0/1
  bool f32ok = true;
  for (int e = 0; e < 16; e++) {
    const unsigned char* q = p + 4 * e;
    bool one  = (q[0] == 0 && q[1] == 0 && q[2] == 0x80 && q[3] == 0x3F);
    bool zero = (q[0] == 0 && q[1] == 0 && q[2] == 0 && q[3] == 0);
    if (!(one || zero)) { f32ok = false; break; }
  }
  return f32ok ? 2 : 0;
}

__device__ inline int maskbit(const unsigned char* p, int idx, int mode) {
  if (mode == 1) return ((const int*)p)[idx] & 1;
  if (mode == 2) return ((const float*)p)[idx] != 0.0f;
  return p[idx] & 1;
}

__global__ __launch_bounds__(256) void prep_kernel(
    const unsigned char* __restrict__ mask0, const int* __restrict__ thr0,
    const unsigned char* __restrict__ mask1, const unsigned char* __restrict__ mask2,
    signed char* __restrict__ cA, unsigned char* __restrict__ cB,
    unsigned char* __restrict__ Bf, unsigned* __restrict__ M2p) {
  __shared__ int smode;
  if (threadIdx.x == 0) smode = detect_mode(mask1);
  __syncthreads();
  int mode = smode;
  int gid = blockIdx.x * 256 + threadIdx.x;
  if (gid < 524288) {              // cA / cB tables for L0
    int which = gid >> 18;
    int idx = gid & 262143;
    int hw = idx >> 10;
    int o  = idx & 1023;
    int base = which ? 8 : 0;
    int cnt = 0;
#pragma unroll
    for (int i = 0; i < 8; i++) {
      int xb = (hw >> (7 - i)) & 1;                     // MSB-first bits
      int mb = maskbit(mask0, (base + i) * 1024 + o, mode);
      cnt += (xb == mb);
    }
    if (which) cB[idx] = (unsigned char)cnt;
    else       cA[idx] = (signed char)(cnt - thr0[o]);
    return;
  }
  int g1 = gid - 524288;
  if (g1 < 262144) {               // M01 -> Bf fragment layout, bytes +1/-1
    int o  = g1 & 1023;
    int kk = g1 >> 10;             // u32 chunk: feats 4kk..4kk+3
    unsigned u = 0;
#pragma unroll
    for (int j = 0; j < 4; j++)
      u |= (maskbit(mask1, (4 * kk + j) * 1024 + o, mode) ? 0x01u : 0xFFu) << (8 * j);
    unsigned off = ((unsigned)(o >> 5) << 15) + ((unsigned)(kk >> 3) << 10) +
                   ((unsigned)((kk >> 2) & 1) << 9) + ((unsigned)(o & 31) << 4) +
                   ((unsigned)(kk & 3) << 2);
    *reinterpret_cast<unsigned*>(Bf + off) = u;
    return;
  }
  int g2 = g1 - 262144;
  if (g2 < 768) {                  // pack mask2: M2p[o][kw], LSB-first
    int kw = g2 / 24, o = g2 % 24;
    unsigned wv = 0;
    for (int b = 0; b < 32; b++)
      wv |= (unsigned)maskbit(mask2, (kw * 32 + b) * 24 + o, mode) << b;
    M2p[o * 32 + kw] = wv;
  }
}

// popm from +-1 bytes: P = n1 + 8*(1024-n1) -> n1 = (8192 - P) / 7.
__global__ __launch_bounds__(64) void popm_kernel(
    const unsigned char* __restrict__ Bf, const int* __restrict__ thr1,
    int* __restrict__ carr) {
  int o = blockIdx.x;
  int t = threadIdx.x;               // t = ks*2+g
  const uint4* p = reinterpret_cast<const uint4*>(
      Bf + ((unsigned)(o >> 5) << 15) + ((unsigned)(t >> 1) << 10) +
      ((unsigned)(t & 1) << 9) + ((unsigned)(o & 31) << 4));
  uint4 v = *p;
  int s = __popc(v.x) + __popc(v.y) + __popc(v.z) + __popc(v.w);
#pragma unroll
  for (int d = 32; d >= 1; d >>= 1) s += __shfl_down(s, d);
  if (t == 0) {
    int n1 = (8192 - s) / 7;
    carr[o] = thr1[o] + n1 - 1024;
  }
}

// Main: block = 64 px x 1024 outs, 512 threads (8 waves), grid 1024.
// LDS = A-i8 64KB + lbits 8.25KB = 72.3KB -> 2 blocks/CU.
// Wave = 2 rt x 2 oc, 2 passes. R18: ks loop unrolled x4 with 4-deep
// named-slot B prefetch (static indexing; rule: no runtime-indexed reg arrays)
// and 1-deep A prefetch. Prefetch overreads (ks 32..35, c 64..65) land in
// adjacent ws/LDS regions - in-bounds, values unused.
__global__ __launch_bounds__(512) void main_kernel(
    const signed char* __restrict__ cA, const unsigned char* __restrict__ cB,
    const unsigned char* __restrict__ Bf, const int* __restrict__ carr,
    unsigned* __restrict__ X2p) {
  __shared__ v4i Ae4[4096];          // 64 KB  [c=2ks+g 0..63][row 0..63]
  __shared__ unsigned lbits[2112];   // 8.25 KB [row 0..63][wd 0..31] stride 33
  int t = threadIdx.x;
  int lane = t & 63;
  int wv = t >> 6;                   // wave 0..7
  int n0 = blockIdx.x << 6;
  int h = n0 >> 8;                   // constant across the 64-px tile
  int w0 = n0 & 255;

  // ---- L0a: bits via ballot; thread owns features o=t and o=t+512.
  {
    int o1 = t, o2 = t + 512;
    int av1 = (int)cA[h * 1024 + o1];
    int av2 = (int)cA[h * 1024 + o2];
    const unsigned char* cb = cB + (unsigned)w0 * 1024;
#pragma unroll 1
    for (int r4 = 0; r4 < 64; r4 += 4) {
      int v1[4], v2[4];
#pragma unroll
      for (int i = 0; i < 4; i++) {
        v1[i] = (int)cb[(unsigned)(r4 + i) * 1024 + o1];
        v2[i] = (int)cb[(unsigned)(r4 + i) * 1024 + o2];
      }
#pragma unroll
      for (int i = 0; i < 4; i++) {
        int r = r4 + i;
        unsigned long long bal1 = __ballot((av1 + v1[i]) > 0);
        unsigned long long bal2 = __ballot((av2 + v2[i]) > 0);
        if (lane == 0) {
          lbits[r * 33 + wv * 2]          = (unsigned)bal1;
          lbits[r * 33 + wv * 2 + 1]      = (unsigned)(bal1 >> 32);
          lbits[r * 33 + 16 + wv * 2]     = (unsigned)bal2;
          lbits[r * 33 + 16 + wv * 2 + 1] = (unsigned)(bal2 >> 32);
        }
      }
    }
  }
  __syncthreads();

  // ---- L0b: expand bits -> i8 A-tile (8 threads/row x 8 chunks; conflict-free)
  {
    int r = t & 63;
    int c0 = (t >> 6) << 3;
#pragma unroll
    for (int ci = 0; ci < 8; ci++) {
      int c = c0 + ci;               // halfword index 0..63 (= 2ks+g)
      unsigned word = lbits[r * 33 + (c >> 1)];
      unsigned hwv = (c & 1) ? (word >> 16) : (word & 0xFFFFu);
      Ae4[c * 64 + r] = expand16(hwv);
    }
  }
  __syncthreads();

  // ---- L1: MFMA; wave owns oc pair, rt = 2 row-tiles, 4-deep B pipeline.
  int g = lane >> 5;
  int col = lane & 31;

#define LDB(P, KS) (*reinterpret_cast<const v4i*>((P) + (KS) * 1024))
#define STEP(BS0, BS1, KS)                                                   \
  {                                                                          \
    v4i b0 = BS0, b1 = BS1;                                                  \
    BS0 = LDB(bp0, (KS) + 4);                                                \
    BS1 = LDB(bp1, (KS) + 4);                                                \
    v4i a0 = a0c, a1 = a1c;                                                  \
    int cn = 2 * ((KS) + 1) + g;                                             \
    a0c = Ae4[cn * 64 + col];                                                \
    a1c = Ae4[cn * 64 + 32 + col];                                           \
    acc00 = __builtin_amdgcn_mfma_i32_32x32x32_i8(a0, b0, acc00, 0, 0, 0);   \
    acc10 = __builtin_amdgcn_mfma_i32_32x32x32_i8(a1, b0, acc10, 0, 0, 0);   \
    acc01 = __builtin_amdgcn_mfma_i32_32x32x32_i8(a0, b1, acc01, 0, 0, 0);   \
    acc11 = __builtin_amdgcn_mfma_i32_32x32x32_i8(a1, b1, acc11, 0, 0, 0);   \
  }

#pragma unroll 1
  for (int pass = 0; pass < 2; pass++) {
    int ocp = (pass << 4) + (wv << 1);
    const unsigned char* bp0 = Bf + ((unsigned)ocp << 15) + (g << 9) + (col << 4);
    const unsigned char* bp1 = bp0 + 32768;

    v16i acc00 = {0,0,0,0,0,0,0,0,0,0,0,0,0,0,0,0};   // [rt][s]
    v16i acc10 = acc00, acc01 = acc00, acc11 = acc00;

    v4i b0_0 = LDB(bp0, 0), b0_1 = LDB(bp0, 1), b0_2 = LDB(bp0, 2), b0_3 = LDB(bp0, 3);
    v4i b1_0 = LDB(bp1, 0), b1_1 = LDB(bp1, 1), b1_2 = LDB(bp1, 2), b1_3 = LDB(bp1, 3);
    v4i a0c = Ae4[g * 64 + col];
    v4i a1c = Ae4[g * 64 + 32 + col];

#pragma unroll 1
    for (int ks4 = 0; ks4 < 32; ks4 += 4) {
      STEP(b0_0, b1_0, ks4);
      STEP(b0_1, b1_1, ks4 + 1);
      STEP(b0_2, b1_2, ks4 + 2);
      STEP(b0_3, b1_3, ks4 + 3);
    }

    // threshold (av = 2s - popx) + ballot-pack -> X2p
#pragma unroll
    for (int s = 0; s < 2; s++) {
      int oc = ocp + s;
      int cv = carr[(oc << 5) + col];
#pragma unroll
      for (int rt = 0; rt < 2; rt++) {
        v16i av = (s == 0) ? (rt == 0 ? acc00 : acc10)
                           : (rt == 0 ? acc01 : acc11);
#pragma unroll
        for (int reg = 0; reg < 16; reg++) {
          int px_lo = (rt << 5) + (reg & 3) + ((reg >> 2) << 3);
          bool bit = av[reg] > cv;
          unsigned long long bal = __ballot(bit);
          if (lane == 0) {
            X2p[(unsigned)(n0 + px_lo) * 32 + oc]     = (unsigned)bal;
            X2p[(unsigned)(n0 + px_lo + 4) * 32 + oc] = (unsigned)(bal >> 32);
          }
        }
      }
    }
  }
#undef STEP
#undef LDB
}

// Layer 2 + epilogue: 256 px/block, one px/thread.
__global__ __launch_bounds__(256) void l2_kernel(
    const uint4* __restrict__ X2p4, const unsigned* __restrict__ M2p,
    const int* __restrict__ thr2, const float* __restrict__ image,
    float* __restrict__ out) {
  __shared__ unsigned lm2[768];
  int t = threadIdx.x;
  for (int r = t; r < 768; r += 256) lm2[r] = M2p[r];
  __syncthreads();
  int n = blockIdx.x * 256 + t;
  uint4 xw[8];
#pragma unroll
  for (int q = 0; q < 8; q++) xw[q] = X2p4[(unsigned)n * 8 + q];
#pragma unroll
  for (int c = 0; c < 3; c++) {
    int val = 0;
#pragma unroll
    for (int b = 0; b < 8; b++) {
      int o = c * 8 + b;
      const unsigned* m = &lm2[o * 32];
      unsigned acc2 = 0;
#pragma unroll
      for (int q = 0; q < 8; q++) {
        acc2 += __popc(xw[q].x ^ m[q * 4 + 0]);
        acc2 += __popc(xw[q].y ^ m[q * 4 + 1]);
        acc2 += __popc(xw[q].z ^ m[q * 4 + 2]);
        acc2 += __popc(xw[q].w ^ m[q * 4 + 3]);
      }
      int bit = ((int)(1024u - acc2)) > thr2[o];
      val |= bit << (7 - b);                            // MSB-first
    }
    out[c * 65536 + n] = (float)val;
    out[196608 + c * 65536 + n] = (float)val - image[c * 65536 + n];
  }
}

extern "C" void kernel_launch(void* const* d_in, const int* in_sizes, int n_in,
                              void* d_out, int out_size, void* d_ws, size_t ws_size,
                              hipStream_t stream) {
  const float*         image = (const float*)d_in[0];
  const unsigned char* mask0 = (const unsigned char*)d_in[1];
  const int*           thr0  = (const int*)d_in[2];
  const unsigned char* mask1 = (const unsigned char*)d_in[3];
  const int*           thr1  = (const int*)d_in[4];
  const unsigned char* mask2 = (const unsigned char*)d_in[5];
  const int*           thr2  = (const int*)d_in[6];
  char* ws = (char*)d_ws;
  signed char*    cA    = (signed char*)(ws + WS_CA);
  unsigned char*  cB    = (unsigned char*)(ws + WS_CB);
  unsigned*       M2p   = (unsigned*)(ws + WS_M2P);
  int*            carr  = (int*)(ws + WS_CARR);
  unsigned char*  Bf    = (unsigned char*)(ws + WS_BF);
  unsigned*       X2p   = (unsigned*)(ws + WS_X2);
  float* out = (float*)d_out;

  hipLaunchKernelGGL(prep_kernel, dim3(3075), dim3(256), 0, stream,
                     mask0, thr0, mask1, mask2, cA, cB, Bf, M2p);
  hipLaunchKernelGGL(popm_kernel, dim3(1024), dim3(64), 0, stream,
                     Bf, thr1, carr);
  hipLaunchKernelGGL(main_kernel, dim3(1024), dim3(512), 0, stream,
                     cA, cB, Bf, carr, X2p);
  hipLaunchKernelGGL(l2_kernel, dim3(256), dim3(256), 0, stream,
                     (const uint4*)X2p, M2p, thr2, image, out);
}

// Round 19
// 122.257 us; speedup vs baseline: 1.0361x; 1.0361x over previous
//
#include <hip/hip_runtime.h>
#include <stdint.h>

// 3-layer binary net. L0 fused in main. L1 = i8 MFMA with A in {0,1}, B in
// {+1,-1}: dot = 2s - popx directly; threshold = compare vs
// carr[o] = thr1[o] + popm[o] - 1024. L2 in a tiny separate kernel.
// R19: B loads forced into a 4-deep pipeline via asm volatile
// global_load_dwordx4 + counted s_waitcnt vmcnt(6) + sched_barrier(0)
// (compiler provably discards source-level prefetch: R18 VGPR=52 unchanged).
// ws: cA 256K | cB 256K | M2p 3KB | carr 4KB | Bf 1MB (+-1 i8) | X2p 8MB
#define WS_CA   0
#define WS_CB   262144
#define WS_M2P  524288
#define WS_CARR 527360
#define WS_BF   532480
#define WS_X2   1581056

typedef int v4i  __attribute__((ext_vector_type(4)));
typedef int v16i __attribute__((ext_vector_type(16)));

// 16 bits -> 16 i8 bytes (0/1), byte e = bit e (LSB-first)
__device__ __forceinline__ v4i expand16(unsigned h) {
  v4i a;
  a.x = (int)(__umul24(h & 15u,         0x00204081u) & 0x01010101u);
  a.y = (int)(__umul24((h >> 4) & 15u,  0x00204081u) & 0x01010101u);
  a.z = (int)(__umul24((h >> 8) & 15u,  0x00204081u) & 0x01010101u);
  a.w = (int)(__umul24((h >> 12) & 15u, 0x00204081u) & 0x01010101u);
  return a;
}

// ---- mask upload-format sniffing (bool arrays may arrive as u8, i32, or f32) ----
__device__ inline int detect_mode(const unsigned char* p) {
  unsigned nonalign = 0;
  for (int i = 0; i < 64; i++)
    if (i & 3) nonalign |= p[i];
  if (nonalign == 0) return 1;                 // int32 0/1
  bool f32ok = true;
  for (int e = 0; e < 16; e++) {
    const unsigned char* q = p + 4 * e;
    bool one  = (q[0] == 0 && q[1] == 0 && q[2] == 0x80 && q[3] == 0x3F);
    bool zero = (q[0] == 0 && q[1] == 0 && q[2] == 0 && q[3] == 0);
    if (!(one || zero)) { f32ok = false; break; }
  }
  return f32ok ? 2 : 0;
}

__device__ inline int maskbit(const unsigned char* p, int idx, int mode) {
  if (mode == 1) return ((const int*)p)[idx] & 1;
  if (mode == 2) return ((const float*)p)[idx] != 0.0f;
  return p[idx] & 1;
}

__global__ __launch_bounds__(256) void prep_kernel(
    const unsigned char* __restrict__ mask0, const int* __restrict__ thr0,
    const unsigned char* __restrict__ mask1, const unsigned char* __restrict__ mask2,
    signed char* __restrict__ cA, unsigned char* __restrict__ cB,
    unsigned char* __restrict__ Bf, unsigned* __restrict__ M2p) {
  __shared__ int smode;
  if (threadIdx.x == 0) smode = detect_mode(mask1);
  __syncthreads();
  int mode = smode;
  int gid = blockIdx.x * 256 + threadIdx.x;
  if (gid < 524288) {              // cA / cB tables for L0
    int which = gid >> 18;
    int idx = gid & 262143;
    int hw = idx >> 10;
    int o  = idx & 1023;
    int base = which ? 8 : 0;
    int cnt = 0;
#pragma unroll
    for (int i = 0; i < 8; i++) {
      int xb = (hw >> (7 - i)) & 1;                     // MSB-first bits
      int mb = maskbit(mask0, (base + i) * 1024 + o, mode);
      cnt += (xb == mb);
    }
    if (which) cB[idx] = (unsigned char)cnt;
    else       cA[idx] = (signed char)(cnt - thr0[o]);
    return;
  }
  int g1 = gid - 524288;
  if (g1 < 262144) {               // M01 -> Bf fragment layout, bytes +1/-1
    int o  = g1 & 1023;
    int kk = g1 >> 10;             // u32 chunk: feats 4kk..4kk+3
    unsigned u = 0;
#pragma unroll
    for (int j = 0; j < 4; j++)
      u |= (maskbit(mask1, (4 * kk + j) * 1024 + o, mode) ? 0x01u : 0xFFu) << (8 * j);
    unsigned off = ((unsigned)(o >> 5) << 15) + ((unsigned)(kk >> 3) << 10) +
                   ((unsigned)((kk >> 2) & 1) << 9) + ((unsigned)(o & 31) << 4) +
                   ((unsigned)(kk & 3) << 2);
    *reinterpret_cast<unsigned*>(Bf + off) = u;
    return;
  }
  int g2 = g1 - 262144;
  if (g2 < 768) {                  // pack mask2: M2p[o][kw], LSB-first
    int kw = g2 / 24, o = g2 % 24;
    unsigned wv = 0;
    for (int b = 0; b < 32; b++)
      wv |= (unsigned)maskbit(mask2, (kw * 32 + b) * 24 + o, mode) << b;
    M2p[o * 32 + kw] = wv;
  }
}

// popm from +-1 bytes: P = n1 + 8*(1024-n1) -> n1 = (8192 - P) / 7.
__global__ __launch_bounds__(64) void popm_kernel(
    const unsigned char* __restrict__ Bf, const int* __restrict__ thr1,
    int* __restrict__ carr) {
  int o = blockIdx.x;
  int t = threadIdx.x;               // t = ks*2+g
  const uint4* p = reinterpret_cast<const uint4*>(
      Bf + ((unsigned)(o >> 5) << 15) + ((unsigned)(t >> 1) << 10) +
      ((unsigned)(t & 1) << 9) + ((unsigned)(o & 31) << 4));
  uint4 v = *p;
  int s = __popc(v.x) + __popc(v.y) + __popc(v.z) + __popc(v.w);
#pragma unroll
  for (int d = 32; d >= 1; d >>= 1) s += __shfl_down(s, d);
  if (t == 0) {
    int n1 = (8192 - s) / 7;
    carr[o] = thr1[o] + n1 - 1024;
  }
}

// Main: block = 64 px x 1024 outs, 512 threads (8 waves), grid 1024.
// LDS = A-i8 64KB + lbits 8.25KB -> 2 blocks/CU. Wave = 2 rt x 2 oc, 2 passes.
__global__ __launch_bounds__(512) void main_kernel(
    const signed char* __restrict__ cA, const unsigned char* __restrict__ cB,
    const unsigned char* __restrict__ Bf, const int* __restrict__ carr,
    unsigned* __restrict__ X2p) {
  __shared__ v4i Ae4[4096];          // 64 KB  [c=2ks+g 0..63][row 0..63]
  __shared__ unsigned lbits[2112];   // 8.25 KB [row 0..63][wd 0..31] stride 33
  int t = threadIdx.x;
  int lane = t & 63;
  int wv = t >> 6;                   // wave 0..7
  int n0 = blockIdx.x << 6;
  int h = n0 >> 8;                   // constant across the 64-px tile
  int w0 = n0 & 255;

  // ---- L0a: bits via ballot; thread owns features o=t and o=t+512.
  {
    int o1 = t, o2 = t + 512;
    int av1 = (int)cA[h * 1024 + o1];
    int av2 = (int)cA[h * 1024 + o2];
    const unsigned char* cb = cB + (unsigned)w0 * 1024;
#pragma unroll 1
    for (int r4 = 0; r4 < 64; r4 += 4) {
      int v1[4], v2[4];
#pragma unroll
      for (int i = 0; i < 4; i++) {
        v1[i] = (int)cb[(unsigned)(r4 + i) * 1024 + o1];
        v2[i] = (int)cb[(unsigned)(r4 + i) * 1024 + o2];
      }
#pragma unroll
      for (int i = 0; i < 4; i++) {
        int r = r4 + i;
        unsigned long long bal1 = __ballot((av1 + v1[i]) > 0);
        unsigned long long bal2 = __ballot((av2 + v2[i]) > 0);
        if (lane == 0) {
          lbits[r * 33 + wv * 2]          = (unsigned)bal1;
          lbits[r * 33 + wv * 2 + 1]      = (unsigned)(bal1 >> 32);
          lbits[r * 33 + 16 + wv * 2]     = (unsigned)bal2;
          lbits[r * 33 + 16 + wv * 2 + 1] = (unsigned)(bal2 >> 32);
        }
      }
    }
  }
  __syncthreads();

  // ---- L0b: expand bits -> i8 A-tile (8 threads/row x 8 chunks; conflict-free)
  {
    int r = t & 63;
    int c0 = (t >> 6) << 3;
#pragma unroll
    for (int ci = 0; ci < 8; ci++) {
      int c = c0 + ci;               // halfword index 0..63 (= 2ks+g)
      unsigned word = lbits[r * 33 + (c >> 1)];
      unsigned hwv = (c & 1) ? (word >> 16) : (word & 0xFFFFu);
      Ae4[c * 64 + r] = expand16(hwv);
    }
  }
  __syncthreads();

  // ---- L1: MFMA; forced 4-deep B pipeline (asm volatile + counted vmcnt).
  int g = lane >> 5;
  int col = lane & 31;

// two loads, one volatile asm (textual order preserved; cannot be sunk)
#define ISSUE2(S0, S1, P0, P1)                                         \
  asm volatile("global_load_dwordx4 %0, %2, off\n\t"                   \
               "global_load_dwordx4 %1, %3, off"                       \
               : "=&v"(S0), "=&v"(S1)                                  \
               : "v"(P0), "v"(P1));

// consume slot (S0,S1) for step KS; WC = literal vmcnt count; optionally
// issue the KS+4 loads back into the same slots.
#define STEP(S0, S1, KS, WC, DO_ISSUE)                                 \
  {                                                                    \
    asm volatile("s_waitcnt vmcnt(" #WC ")");                          \
    __builtin_amdgcn_sched_barrier(0);                                 \
    int c_ = 2 * (KS) + g;                                             \
    v4i a0_ = Ae4[c_ * 64 + col];                                      \
    v4i a1_ = Ae4[c_ * 64 + 32 + col];                                 \
    __builtin_amdgcn_s_setprio(1);                                     \
    acc00 = __builtin_amdgcn_mfma_i32_32x32x32_i8(a0_, S0, acc00, 0, 0, 0); \
    acc10 = __builtin_amdgcn_mfma_i32_32x32x32_i8(a1_, S0, acc10, 0, 0, 0); \
    acc01 = __builtin_amdgcn_mfma_i32_32x32x32_i8(a0_, S1, acc01, 0, 0, 0); \
    acc11 = __builtin_amdgcn_mfma_i32_32x32x32_i8(a1_, S1, acc11, 0, 0, 0); \
    __builtin_amdgcn_s_setprio(0);                                     \
    if (DO_ISSUE) {                                                    \
      ISSUE2(S0, S1, bp0 + ((KS) + 4) * 1024, bp1 + ((KS) + 4) * 1024) \
    }                                                                  \
  }

#pragma unroll 1
  for (int pass = 0; pass < 2; pass++) {
    int ocp = (pass << 4) + (wv << 1);
    const unsigned char* bp0 = Bf + ((unsigned)ocp << 15) + (g << 9) + (col << 4);
    const unsigned char* bp1 = bp0 + 32768;

    v16i acc00 = {0,0,0,0,0,0,0,0,0,0,0,0,0,0,0,0};   // [rt][s]
    v16i acc10 = acc00, acc01 = acc00, acc11 = acc00;

    asm volatile("s_waitcnt vmcnt(0)");    // isolate from prior stores
    v4i b00, b01, b02, b03, b10, b11, b12, b13;
    ISSUE2(b00, b10, bp0,        bp1)
    ISSUE2(b01, b11, bp0 + 1024, bp1 + 1024)
    ISSUE2(b02, b12, bp0 + 2048, bp1 + 2048)
    ISSUE2(b03, b13, bp0 + 3072, bp1 + 3072)

#pragma unroll 1
    for (int ks4 = 0; ks4 < 28; ks4 += 4) {
      STEP(b00, b10, ks4 + 0, 6, 1)
      STEP(b01, b11, ks4 + 1, 6, 1)
      STEP(b02, b12, ks4 + 2, 6, 1)
      STEP(b03, b13, ks4 + 3, 6, 1)
    }
    STEP(b00, b10, 28, 6, 0)
    STEP(b01, b11, 29, 4, 0)
    STEP(b02, b12, 30, 2, 0)
    STEP(b03, b13, 31, 0, 0)

    // threshold (av = 2s - popx) + ballot-pack -> X2p
#pragma unroll
    for (int s = 0; s < 2; s++) {
      int oc = ocp + s;
      int cv = carr[(oc << 5) + col];
#pragma unroll
      for (int rt = 0; rt < 2; rt++) {
        v16i av = (s == 0) ? (rt == 0 ? acc00 : acc10)
                           : (rt == 0 ? acc01 : acc11);
#pragma unroll
        for (int reg = 0; reg < 16; reg++) {
          int px_lo = (rt << 5) + (reg & 3) + ((reg >> 2) << 3);
          bool bit = av[reg] > cv;
          unsigned long long bal = __ballot(bit);
          if (lane == 0) {
            X2p[(unsigned)(n0 + px_lo) * 32 + oc]     = (unsigned)bal;
            X2p[(unsigned)(n0 + px_lo + 4) * 32 + oc] = (unsigned)(bal >> 32);
          }
        }
      }
    }
  }
#undef STEP
#undef ISSUE2
}

// Layer 2 + epilogue: 256 px/block, one px/thread.
__global__ __launch_bounds__(256) void l2_kernel(
    const uint4* __restrict__ X2p4, const unsigned* __restrict__ M2p,
    const int* __restrict__ thr2, const float* __restrict__ image,
    float* __restrict__ out) {
  __shared__ unsigned lm2[768];
  int t = threadIdx.x;
  for (int r = t; r < 768; r += 256) lm2[r] = M2p[r];
  __syncthreads();
  int n = blockIdx.x * 256 + t;
  uint4 xw[8];
#pragma unroll
  for (int q = 0; q < 8; q++) xw[q] = X2p4[(unsigned)n * 8 + q];
#pragma unroll
  for (int c = 0; c < 3; c++) {
    int val = 0;
#pragma unroll
    for (int b = 0; b < 8; b++) {
      int o = c * 8 + b;
      const unsigned* m = &lm2[o * 32];
      unsigned acc2 = 0;
#pragma unroll
      for (int q = 0; q < 8; q++) {
        acc2 += __popc(xw[q].x ^ m[q * 4 + 0]);
        acc2 += __popc(xw[q].y ^ m[q * 4 + 1]);
        acc2 += __popc(xw[q].z ^ m[q * 4 + 2]);
        acc2 += __popc(xw[q].w ^ m[q * 4 + 3]);
      }
      int bit = ((int)(1024u - acc2)) > thr2[o];
      val |= bit << (7 - b);                            // MSB-first
    }
    out[c * 65536 + n] = (float)val;
    out[196608 + c * 65536 + n] = (float)val - image[c * 65536 + n];
  }
}

extern "C" void kernel_launch(void* const* d_in, const int* in_sizes, int n_in,
                              void* d_out, int out_size, void* d_ws, size_t ws_size,
                              hipStream_t stream) {
  const float*         image = (const float*)d_in[0];
  const unsigned char* mask0 = (const unsigned char*)d_in[1];
  const int*           thr0  = (const int*)d_in[2];
  const unsigned char* mask1 = (const unsigned char*)d_in[3];
  const int*           thr1  = (const int*)d_in[4];
  const unsigned char* mask2 = (const unsigned char*)d_in[5];
  const int*           thr2  = (const int*)d_in[6];
  char* ws = (char*)d_ws;
  signed char*    cA    = (signed char*)(ws + WS_CA);
  unsigned char*  cB    = (unsigned char*)(ws + WS_CB);
  unsigned*       M2p   = (unsigned*)(ws + WS_M2P);
  int*            carr  = (int*)(ws + WS_CARR);
  unsigned char*  Bf    = (unsigned char*)(ws + WS_BF);
  unsigned*       X2p   = (unsigned*)(ws + WS_X2);
  float* out = (float*)d_out;

  hipLaunchKernelGGL(prep_kernel, dim3(3075), dim3(256), 0, stream,
                     mask0, thr0, mask1, mask2, cA, cB, Bf, M2p);
  hipLaunchKernelGGL(popm_kernel, dim3(1024), dim3(64), 0, stream,
                     Bf, thr1, carr);
  hipLaunchKernelGGL(main_kernel, dim3(1024), dim3(512), 0, stream,
                     cA, cB, Bf, carr, X2p);
  hipLaunchKernelGGL(l2_kernel, dim3(256), dim3(256), 0, stream,
                     (const uint4*)X2p, M2p, thr2, image, out);
}

// Round 20
// 120.836 us; speedup vs baseline: 1.0483x; 1.0118x over previous
//
#include <hip/hip_runtime.h>
#include <stdint.h>

// 3-layer binary net. L0 fused in main. L1 = i8 MFMA with A in {0,1}, B in
// {+1,-1}: dot = 2s - popx directly; threshold = compare vs
// carr[o] = thr1[o] + popm[o] - 1024. L2 in a tiny separate kernel.
// R20: A-tile processed in K-quarters (16KB LDS) re-expanded per pass ->
// LDS 24.25KB/block -> 4 blocks/CU = 32 waves/CU (HW max TLP).
// ws: cA 256K | cB 256K | M2p 3KB | carr 4KB | Bf 1MB (+-1 i8) | X2p 8MB
#define WS_CA   0
#define WS_CB   262144
#define WS_M2P  524288
#define WS_CARR 527360
#define WS_BF   532480
#define WS_X2   1581056

typedef int v4i  __attribute__((ext_vector_type(4)));
typedef int v16i __attribute__((ext_vector_type(16)));

// 16 bits -> 16 i8 bytes (0/1), byte e = bit e (LSB-first)
__device__ __forceinline__ v4i expand16(unsigned h) {
  v4i a;
  a.x = (int)(__umul24(h & 15u,         0x00204081u) & 0x01010101u);
  a.y = (int)(__umul24((h >> 4) & 15u,  0x00204081u) & 0x01010101u);
  a.z = (int)(__umul24((h >> 8) & 15u,  0x00204081u) & 0x01010101u);
  a.w = (int)(__umul24((h >> 12) & 15u, 0x00204081u) & 0x01010101u);
  return a;
}

// ---- mask upload-format sniffing (bool arrays may arrive as u8, i32, or f32) ----
__device__ inline int detect_mode(const unsigned char* p) {
  unsigned nonalign = 0;
  for (int i = 0; i < 64; i++)
    if (i & 3) nonalign |= p[i];
  if (nonalign == 0) return 1;                 // int32 0/1
  bool f32ok = true;
  for (int e = 0; e < 16; e++) {
    const unsigned char* q = p + 4 * e;
    bool one  = (q[0] == 0 && q[1] == 0 && q[2] == 0x80 && q[3] == 0x3F);
    bool zero = (q[0] == 0 && q[1] == 0 && q[2] == 0 && q[3] == 0);
    if (!(one || zero)) { f32ok = false; break; }
  }
  return f32ok ? 2 : 0;
}

__device__ inline int maskbit(const unsigned char* p, int idx, int mode) {
  if (mode == 1) return ((const int*)p)[idx] & 1;
  if (mode == 2) return ((const float*)p)[idx] != 0.0f;
  return p[idx] & 1;
}

__global__ __launch_bounds__(256) void prep_kernel(
    const unsigned char* __restrict__ mask0, const int* __restrict__ thr0,
    const unsigned char* __restrict__ mask1, const unsigned char* __restrict__ mask2,
    signed char* __restrict__ cA, unsigned char* __restrict__ cB,
    unsigned char* __restrict__ Bf, unsigned* __restrict__ M2p) {
  __shared__ int smode;
  if (threadIdx.x == 0) smode = detect_mode(mask1);
  __syncthreads();
  int mode = smode;
  int gid = blockIdx.x * 256 + threadIdx.x;
  if (gid < 524288) {              // cA / cB tables for L0
    int which = gid >> 18;
    int idx = gid & 262143;
    int hw = idx >> 10;
    int o  = idx & 1023;
    int base = which ? 8 : 0;
    int cnt = 0;
#pragma unroll
    for (int i = 0; i < 8; i++) {
      int xb = (hw >> (7 - i)) & 1;                     // MSB-first bits
      int mb = maskbit(mask0, (base + i) * 1024 + o, mode);
      cnt += (xb == mb);
    }
    if (which) cB[idx] = (unsigned char)cnt;
    else       cA[idx] = (signed char)(cnt - thr0[o]);
    return;
  }
  int g1 = gid - 524288;
  if (g1 < 262144) {               // M01 -> Bf fragment layout, bytes +1/-1
    int o  = g1 & 1023;
    int kk = g1 >> 10;             // u32 chunk: feats 4kk..4kk+3
    unsigned u = 0;
#pragma unroll
    for (int j = 0; j < 4; j++)
      u |= (maskbit(mask1, (4 * kk + j) * 1024 + o, mode) ? 0x01u : 0xFFu) << (8 * j);
    unsigned off = ((unsigned)(o >> 5) << 15) + ((unsigned)(kk >> 3) << 10) +
                   ((unsigned)((kk >> 2) & 1) << 9) + ((unsigned)(o & 31) << 4) +
                   ((unsigned)(kk & 3) << 2);
    *reinterpret_cast<unsigned*>(Bf + off) = u;
    return;
  }
  int g2 = g1 - 262144;
  if (g2 < 768) {                  // pack mask2: M2p[o][kw], LSB-first
    int kw = g2 / 24, o = g2 % 24;
    unsigned wv = 0;
    for (int b = 0; b < 32; b++)
      wv |= (unsigned)maskbit(mask2, (kw * 32 + b) * 24 + o, mode) << b;
    M2p[o * 32 + kw] = wv;
  }
}

// popm from +-1 bytes: P = n1 + 8*(1024-n1) -> n1 = (8192 - P) / 7.
__global__ __launch_bounds__(64) void popm_kernel(
    const unsigned char* __restrict__ Bf, const int* __restrict__ thr1,
    int* __restrict__ carr) {
  int o = blockIdx.x;
  int t = threadIdx.x;               // t = ks*2+g
  const uint4* p = reinterpret_cast<const uint4*>(
      Bf + ((unsigned)(o >> 5) << 15) + ((unsigned)(t >> 1) << 10) +
      ((unsigned)(t & 1) << 9) + ((unsigned)(o & 31) << 4));
  uint4 v = *p;
  int s = __popc(v.x) + __popc(v.y) + __popc(v.z) + __popc(v.w);
#pragma unroll
  for (int d = 32; d >= 1; d >>= 1) s += __shfl_down(s, d);
  if (t == 0) {
    int n1 = (8192 - s) / 7;
    carr[o] = thr1[o] + n1 - 1024;
  }
}

// Main: block = 64 px x 1024 outs, 512 threads (8 waves), grid 1024
// (= exactly 4 blocks/CU x 256 CU, one full round).
// LDS = A-quarter 16KB + lbits 8.25KB = 24.25KB -> 4 blocks/CU, 8 waves/SIMD.
// Per pass (oc pair per wave): for each K-quarter {barrier, expand 16 chunks,
// barrier, 8 MFMA steps}; acc lives across quarters; epilogue -> X2p.
__global__ __launch_bounds__(512) void main_kernel(
    const signed char* __restrict__ cA, const unsigned char* __restrict__ cB,
    const unsigned char* __restrict__ Bf, const int* __restrict__ carr,
    unsigned* __restrict__ X2p) {
  __shared__ v4i Ae4[1024];          // 16 KB  [cl 0..15][row 0..63]
  __shared__ unsigned lbits[2112];   // 8.25 KB [row 0..63][wd 0..31] stride 33
  int t = threadIdx.x;
  int lane = t & 63;
  int wv = t >> 6;                   // wave 0..7
  int n0 = blockIdx.x << 6;
  int h = n0 >> 8;                   // constant across the 64-px tile
  int w0 = n0 & 255;

  // ---- L0a: bits via ballot; thread owns features o=t and o=t+512.
  {
    int o1 = t, o2 = t + 512;
    int av1 = (int)cA[h * 1024 + o1];
    int av2 = (int)cA[h * 1024 + o2];
    const unsigned char* cb = cB + (unsigned)w0 * 1024;
#pragma unroll 1
    for (int r4 = 0; r4 < 64; r4 += 4) {
      int v1[4], v2[4];
#pragma unroll
      for (int i = 0; i < 4; i++) {
        v1[i] = (int)cb[(unsigned)(r4 + i) * 1024 + o1];
        v2[i] = (int)cb[(unsigned)(r4 + i) * 1024 + o2];
      }
#pragma unroll
      for (int i = 0; i < 4; i++) {
        int r = r4 + i;
        unsigned long long bal1 = __ballot((av1 + v1[i]) > 0);
        unsigned long long bal2 = __ballot((av2 + v2[i]) > 0);
        if (lane == 0) {
          lbits[r * 33 + wv * 2]          = (unsigned)bal1;
          lbits[r * 33 + wv * 2 + 1]      = (unsigned)(bal1 >> 32);
          lbits[r * 33 + 16 + wv * 2]     = (unsigned)bal2;
          lbits[r * 33 + 16 + wv * 2 + 1] = (unsigned)(bal2 >> 32);
        }
      }
    }
  }

  int g = lane >> 5;
  int col = lane & 31;
  int r_ex = t & 63;                 // expand: row
  int cl0  = (t >> 6) << 1;          // expand: first of 2 chunks

#pragma unroll 1
  for (int pass = 0; pass < 2; pass++) {
    int ocp = (pass << 4) + (wv << 1);
    const unsigned char* bp0 = Bf + ((unsigned)ocp << 15) + (g << 9) + (col << 4);
    const unsigned char* bp1 = bp0 + 32768;

    v16i acc00 = {0,0,0,0,0,0,0,0,0,0,0,0,0,0,0,0};   // [rt][s]
    v16i acc10 = acc00, acc01 = acc00, acc11 = acc00;

#pragma unroll 1
    for (int kq = 0; kq < 4; kq++) {
      // expand quarter kq: chunks c_global = kq*16 + cl, cl = 0..15
      __syncthreads();               // prior quarter's MFMA reads done
#pragma unroll
      for (int ci = 0; ci < 2; ci++) {
        int cl = cl0 + ci;
        unsigned word = lbits[r_ex * 33 + (kq << 3) + (cl >> 1)];
        unsigned hwv = (cl & 1) ? (word >> 16) : (word & 0xFFFFu);
        Ae4[cl * 64 + r_ex] = expand16(hwv);
      }
      __syncthreads();               // A-quarter ready

      int ksb = kq << 3;             // global ks base
      v4i b0n = *reinterpret_cast<const v4i*>(bp0 + (ksb) * 1024);
      v4i b1n = *reinterpret_cast<const v4i*>(bp1 + (ksb) * 1024);
#pragma unroll 1
      for (int ksl = 0; ksl < 8; ksl++) {
        v4i b0 = b0n, b1 = b1n;
        if (ksl < 7) {
          b0n = *reinterpret_cast<const v4i*>(bp0 + (ksb + ksl + 1) * 1024);
          b1n = *reinterpret_cast<const v4i*>(bp1 + (ksb + ksl + 1) * 1024);
        }
        int c = 2 * ksl + g;
        v4i a0 = Ae4[c * 64 + col];
        v4i a1 = Ae4[c * 64 + 32 + col];
        acc00 = __builtin_amdgcn_mfma_i32_32x32x32_i8(a0, b0, acc00, 0, 0, 0);
        acc10 = __builtin_amdgcn_mfma_i32_32x32x32_i8(a1, b0, acc10, 0, 0, 0);
        acc01 = __builtin_amdgcn_mfma_i32_32x32x32_i8(a0, b1, acc01, 0, 0, 0);
        acc11 = __builtin_amdgcn_mfma_i32_32x32x32_i8(a1, b1, acc11, 0, 0, 0);
      }
    }

    // threshold (av = 2s - popx) + ballot-pack -> X2p
#pragma unroll
    for (int s = 0; s < 2; s++) {
      int oc = ocp + s;
      int cv = carr[(oc << 5) + col];
#pragma unroll
      for (int rt = 0; rt < 2; rt++) {
        v16i av = (s == 0) ? (rt == 0 ? acc00 : acc10)
                           : (rt == 0 ? acc01 : acc11);
#pragma unroll
        for (int reg = 0; reg < 16; reg++) {
          int px_lo = (rt << 5) + (reg & 3) + ((reg >> 2) << 3);
          bool bit = av[reg] > cv;
          unsigned long long bal = __ballot(bit);
          if (lane == 0) {
            X2p[(unsigned)(n0 + px_lo) * 32 + oc]     = (unsigned)bal;
            X2p[(unsigned)(n0 + px_lo + 4) * 32 + oc] = (unsigned)(bal >> 32);
          }
        }
      }
    }
  }
}

// Layer 2 + epilogue: 256 px/block, one px/thread.
__global__ __launch_bounds__(256) void l2_kernel(
    const uint4* __restrict__ X2p4, const unsigned* __restrict__ M2p,
    const int* __restrict__ thr2, const float* __restrict__ image,
    float* __restrict__ out) {
  __shared__ unsigned lm2[768];
  int t = threadIdx.x;
  for (int r = t; r < 768; r += 256) lm2[r] = M2p[r];
  __syncthreads();
  int n = blockIdx.x * 256 + t;
  uint4 xw[8];
#pragma unroll
  for (int q = 0; q < 8; q++) xw[q] = X2p4[(unsigned)n * 8 + q];
#pragma unroll
  for (int c = 0; c < 3; c++) {
    int val = 0;
#pragma unroll
    for (int b = 0; b < 8; b++) {
      int o = c * 8 + b;
      const unsigned* m = &lm2[o * 32];
      unsigned acc2 = 0;
#pragma unroll
      for (int q = 0; q < 8; q++) {
        acc2 += __popc(xw[q].x ^ m[q * 4 + 0]);
        acc2 += __popc(xw[q].y ^ m[q * 4 + 1]);
        acc2 += __popc(xw[q].z ^ m[q * 4 + 2]);
        acc2 += __popc(xw[q].w ^ m[q * 4 + 3]);
      }
      int bit = ((int)(1024u - acc2)) > thr2[o];
      val |= bit << (7 - b);                            // MSB-first
    }
    out[c * 65536 + n] = (float)val;
    out[196608 + c * 65536 + n] = (float)val - image[c * 65536 + n];
  }
}

extern "C" void kernel_launch(void* const* d_in, const int* in_sizes, int n_in,
                              void* d_out, int out_size, void* d_ws, size_t ws_size,
                              hipStream_t stream) {
  const float*         image = (const float*)d_in[0];
  const unsigned char* mask0 = (const unsigned char*)d_in[1];
  const int*           thr0  = (const int*)d_in[2];
  const unsigned char* mask1 = (const unsigned char*)d_in[3];
  const int*           thr1  = (const int*)d_in[4];
  const unsigned char* mask2 = (const unsigned char*)d_in[5];
  const int*           thr2  = (const int*)d_in[6];
  char* ws = (char*)d_ws;
  signed char*    cA    = (signed char*)(ws + WS_CA);
  unsigned char*  cB    = (unsigned char*)(ws + WS_CB);
  unsigned*       M2p   = (unsigned*)(ws + WS_M2P);
  int*            carr  = (int*)(ws + WS_CARR);
  unsigned char*  Bf    = (unsigned char*)(ws + WS_BF);
  unsigned*       X2p   = (unsigned*)(ws + WS_X2);
  float* out = (float*)d_out;

  hipLaunchKernelGGL(prep_kernel, dim3(3075), dim3(256), 0, stream,
                     mask0, thr0, mask1, mask2, cA, cB, Bf, M2p);
  hipLaunchKernelGGL(popm_kernel, dim3(1024), dim3(64), 0, stream,
                     Bf, thr1, carr);
  hipLaunchKernelGGL(main_kernel, dim3(1024), dim3(512), 0, stream,
                     cA, cB, Bf, carr, X2p);
  hipLaunchKernelGGL(l2_kernel, dim3(256), dim3(256), 0, stream,
                     (const uint4*)X2p, M2p, thr2, image, out);
}

// Round 21
// 120.227 us; speedup vs baseline: 1.0536x; 1.0051x over previous
//
#include <hip/hip_runtime.h>
#include <stdint.h>

// 3-layer binary net. L0 fused in main. L1 = i8 MFMA with A in {0,1}, B in
// {+1,-1}: dot = 2s - popx; threshold = compare vs carr = thr1 + popm - 1024.
// R21: L2 de-hotspot — rotate oc assignment by (bid&7) and K-quarter order by
// (bid>>3)&3 so co-resident blocks sweep DIFFERENT parts of the 1MB Bf at any
// instant (R12-R20 all swept in lockstep -> effective L2 BW ~10 TB/s).
// ws: cA 256K | cB 256K | M2p 3KB | carr 4KB | Bf 1MB (+-1 i8) | X2p 8MB
#define WS_CA   0
#define WS_CB   262144
#define WS_M2P  524288
#define WS_CARR 527360
#define WS_BF   532480
#define WS_X2   1581056

typedef int v4i  __attribute__((ext_vector_type(4)));
typedef int v16i __attribute__((ext_vector_type(16)));

// 16 bits -> 16 i8 bytes (0/1), byte e = bit e (LSB-first)
__device__ __forceinline__ v4i expand16(unsigned h) {
  v4i a;
  a.x = (int)(__umul24(h & 15u,         0x00204081u) & 0x01010101u);
  a.y = (int)(__umul24((h >> 4) & 15u,  0x00204081u) & 0x01010101u);
  a.z = (int)(__umul24((h >> 8) & 15u,  0x00204081u) & 0x01010101u);
  a.w = (int)(__umul24((h >> 12) & 15u, 0x00204081u) & 0x01010101u);
  return a;
}

// ---- mask upload-format sniffing (bool arrays may arrive as u8, i32, or f32) ----
__device__ inline int detect_mode(const unsigned char* p) {
  unsigned nonalign = 0;
  for (int i = 0; i < 64; i++)
    if (i & 3) nonalign |= p[i];
  if (nonalign == 0) return 1;                 // int32 0/1
  bool f32ok = true;
  for (int e = 0; e < 16; e++) {
    const unsigned char* q = p + 4 * e;
    bool one  = (q[0] == 0 && q[1] == 0 && q[2] == 0x80 && q[3] == 0x3F);
    bool zero = (q[0] == 0 && q[1] == 0 && q[2] == 0 && q[3] == 0);
    if (!(one || zero)) { f32ok = false; break; }
  }
  return f32ok ? 2 : 0;
}

__device__ inline int maskbit(const unsigned char* p, int idx, int mode) {
  if (mode == 1) return ((const int*)p)[idx] & 1;
  if (mode == 2) return ((const float*)p)[idx] != 0.0f;
  return p[idx] & 1;
}

__global__ __launch_bounds__(256) void prep_kernel(
    const unsigned char* __restrict__ mask0, const int* __restrict__ thr0,
    const unsigned char* __restrict__ mask1, const unsigned char* __restrict__ mask2,
    signed char* __restrict__ cA, unsigned char* __restrict__ cB,
    unsigned char* __restrict__ Bf, unsigned* __restrict__ M2p) {
  __shared__ int smode;
  if (threadIdx.x == 0) smode = detect_mode(mask1);
  __syncthreads();
  int mode = smode;
  int gid = blockIdx.x * 256 + threadIdx.x;
  if (gid < 524288) {              // cA / cB tables for L0
    int which = gid >> 18;
    int idx = gid & 262143;
    int hw = idx >> 10;
    int o  = idx & 1023;
    int base = which ? 8 : 0;
    int cnt = 0;
#pragma unroll
    for (int i = 0; i < 8; i++) {
      int xb = (hw >> (7 - i)) & 1;                     // MSB-first bits
      int mb = maskbit(mask0, (base + i) * 1024 + o, mode);
      cnt += (xb == mb);
    }
    if (which) cB[idx] = (unsigned char)cnt;
    else       cA[idx] = (signed char)(cnt - thr0[o]);
    return;
  }
  int g1 = gid - 524288;
  if (g1 < 262144) {               // M01 -> Bf fragment layout, bytes +1/-1
    int o  = g1 & 1023;
    int kk = g1 >> 10;             // u32 chunk: feats 4kk..4kk+3
    unsigned u = 0;
#pragma unroll
    for (int j = 0; j < 4; j++)
      u |= (maskbit(mask1, (4 * kk + j) * 1024 + o, mode) ? 0x01u : 0xFFu) << (8 * j);
    unsigned off = ((unsigned)(o >> 5) << 15) + ((unsigned)(kk >> 3) << 10) +
                   ((unsigned)((kk >> 2) & 1) << 9) + ((unsigned)(o & 31) << 4) +
                   ((unsigned)(kk & 3) << 2);
    *reinterpret_cast<unsigned*>(Bf + off) = u;
    return;
  }
  int g2 = g1 - 262144;
  if (g2 < 768) {                  // pack mask2: M2p[o][kw], LSB-first
    int kw = g2 / 24, o = g2 % 24;
    unsigned wv = 0;
    for (int b = 0; b < 32; b++)
      wv |= (unsigned)maskbit(mask2, (kw * 32 + b) * 24 + o, mode) << b;
    M2p[o * 32 + kw] = wv;
  }
}

// popm from +-1 bytes: P = n1 + 8*(1024-n1) -> n1 = (8192 - P) / 7.
__global__ __launch_bounds__(64) void popm_kernel(
    const unsigned char* __restrict__ Bf, const int* __restrict__ thr1,
    int* __restrict__ carr) {
  int o = blockIdx.x;
  int t = threadIdx.x;               // t = ks*2+g
  const uint4* p = reinterpret_cast<const uint4*>(
      Bf + ((unsigned)(o >> 5) << 15) + ((unsigned)(t >> 1) << 10) +
      ((unsigned)(t & 1) << 9) + ((unsigned)(o & 31) << 4));
  uint4 v = *p;
  int s = __popc(v.x) + __popc(v.y) + __popc(v.z) + __popc(v.w);
#pragma unroll
  for (int d = 32; d >= 1; d >>= 1) s += __shfl_down(s, d);
  if (t == 0) {
    int n1 = (8192 - s) / 7;
    carr[o] = thr1[o] + n1 - 1024;
  }
}

// Main: block = 64 px x 1024 outs, 512 threads (8 waves), grid 1024.
// LDS = A-quarter 16KB + lbits 8.25KB -> regs (56V+64A) bind at 4 waves/SIMD.
// R21 rotations: ocp = (pass<<4) + (((wv+bid)&7)<<1)  [bijective over wv],
// kq_eff = (kq + (bid>>3)) & 3  [bijective over kq]. Accumulation is
// k-order-independent; coverage of all 32 oc chunks unchanged.
__global__ __launch_bounds__(512) void main_kernel(
    const signed char* __restrict__ cA, const unsigned char* __restrict__ cB,
    const unsigned char* __restrict__ Bf, const int* __restrict__ carr,
    unsigned* __restrict__ X2p) {
  __shared__ v4i Ae4[1024];          // 16 KB  [cl 0..15][row 0..63]
  __shared__ unsigned lbits[2112];   // 8.25 KB [row 0..63][wd 0..31] stride 33
  int t = threadIdx.x;
  int lane = t & 63;
  int wv = t >> 6;                   // wave 0..7
  int bid = blockIdx.x;
  int n0 = bid << 6;
  int h = n0 >> 8;                   // constant across the 64-px tile
  int w0 = n0 & 255;
  int ocrot = bid & 7;
  int kqrot = (bid >> 3) & 3;

  // ---- L0a: bits via ballot; thread owns features o=t and o=t+512.
  {
    int o1 = t, o2 = t + 512;
    int av1 = (int)cA[h * 1024 + o1];
    int av2 = (int)cA[h * 1024 + o2];
    const unsigned char* cb = cB + (unsigned)w0 * 1024;
#pragma unroll 1
    for (int r4 = 0; r4 < 64; r4 += 4) {
      int v1[4], v2[4];
#pragma unroll
      for (int i = 0; i < 4; i++) {
        v1[i] = (int)cb[(unsigned)(r4 + i) * 1024 + o1];
        v2[i] = (int)cb[(unsigned)(r4 + i) * 1024 + o2];
      }
#pragma unroll
      for (int i = 0; i < 4; i++) {
        int r = r4 + i;
        unsigned long long bal1 = __ballot((av1 + v1[i]) > 0);
        unsigned long long bal2 = __ballot((av2 + v2[i]) > 0);
        if (lane == 0) {
          lbits[r * 33 + wv * 2]          = (unsigned)bal1;
          lbits[r * 33 + wv * 2 + 1]      = (unsigned)(bal1 >> 32);
          lbits[r * 33 + 16 + wv * 2]     = (unsigned)bal2;
          lbits[r * 33 + 16 + wv * 2 + 1] = (unsigned)(bal2 >> 32);
        }
      }
    }
  }

  int g = lane >> 5;
  int col = lane & 31;
  int r_ex = t & 63;                 // expand: row
  int cl0  = (t >> 6) << 1;          // expand: first of 2 chunks

#pragma unroll 1
  for (int pass = 0; pass < 2; pass++) {
    int ocp = (pass << 4) + (((wv + ocrot) & 7) << 1);   // rotated oc pair
    const unsigned char* bp0 = Bf + ((unsigned)ocp << 15) + (g << 9) + (col << 4);
    const unsigned char* bp1 = bp0 + 32768;

    v16i acc00 = {0,0,0,0,0,0,0,0,0,0,0,0,0,0,0,0};   // [rt][s]
    v16i acc10 = acc00, acc01 = acc00, acc11 = acc00;

#pragma unroll 1
    for (int kq = 0; kq < 4; kq++) {
      int kqe = (kq + kqrot) & 3;    // rotated quarter
      __syncthreads();               // prior quarter's MFMA reads done
#pragma unroll
      for (int ci = 0; ci < 2; ci++) {
        int cl = cl0 + ci;
        unsigned word = lbits[r_ex * 33 + (kqe << 3) + (cl >> 1)];
        unsigned hwv = (cl & 1) ? (word >> 16) : (word & 0xFFFFu);
        Ae4[cl * 64 + r_ex] = expand16(hwv);
      }
      __syncthreads();               // A-quarter ready

      int ksb = kqe << 3;            // global ks base
      v4i b0n = *reinterpret_cast<const v4i*>(bp0 + (ksb) * 1024);
      v4i b1n = *reinterpret_cast<const v4i*>(bp1 + (ksb) * 1024);
#pragma unroll 1
      for (int ksl = 0; ksl < 8; ksl++) {
        v4i b0 = b0n, b1 = b1n;
        if (ksl < 7) {
          b0n = *reinterpret_cast<const v4i*>(bp0 + (ksb + ksl + 1) * 1024);
          b1n = *reinterpret_cast<const v4i*>(bp1 + (ksb + ksl + 1) * 1024);
        }
        int c = 2 * ksl + g;
        v4i a0 = Ae4[c * 64 + col];
        v4i a1 = Ae4[c * 64 + 32 + col];
        acc00 = __builtin_amdgcn_mfma_i32_32x32x32_i8(a0, b0, acc00, 0, 0, 0);
        acc10 = __builtin_amdgcn_mfma_i32_32x32x32_i8(a1, b0, acc10, 0, 0, 0);
        acc01 = __builtin_amdgcn_mfma_i32_32x32x32_i8(a0, b1, acc01, 0, 0, 0);
        acc11 = __builtin_amdgcn_mfma_i32_32x32x32_i8(a1, b1, acc11, 0, 0, 0);
      }
    }

    // threshold (av = 2s - popx) + ballot-pack -> X2p
#pragma unroll
    for (int s = 0; s < 2; s++) {
      int oc = ocp + s;
      int cv = carr[(oc << 5) + col];
#pragma unroll
      for (int rt = 0; rt < 2; rt++) {
        v16i av = (s == 0) ? (rt == 0 ? acc00 : acc10)
                           : (rt == 0 ? acc01 : acc11);
#pragma unroll
        for (int reg = 0; reg < 16; reg++) {
          int px_lo = (rt << 5) + (reg & 3) + ((reg >> 2) << 3);
          bool bit = av[reg] > cv;
          unsigned long long bal = __ballot(bit);
          if (lane == 0) {
            X2p[(unsigned)(n0 + px_lo) * 32 + oc]     = (unsigned)bal;
            X2p[(unsigned)(n0 + px_lo + 4) * 32 + oc] = (unsigned)(bal >> 32);
          }
        }
      }
    }
  }
}

// Layer 2 + epilogue: 256 px/block, one px/thread.
__global__ __launch_bounds__(256) void l2_kernel(
    const uint4* __restrict__ X2p4, const unsigned* __restrict__ M2p,
    const int* __restrict__ thr2, const float* __restrict__ image,
    float* __restrict__ out) {
  __shared__ unsigned lm2[768];
  int t = threadIdx.x;
  for (int r = t; r < 768; r += 256) lm2[r] = M2p[r];
  __syncthreads();
  int n = blockIdx.x * 256 + t;
  uint4 xw[8];
#pragma unroll
  for (int q = 0; q < 8; q++) xw[q] = X2p4[(unsigned)n * 8 + q];
#pragma unroll
  for (int c = 0; c < 3; c++) {
    int val = 0;
#pragma unroll
    for (int b = 0; b < 8; b++) {
      int o = c * 8 + b;
      const unsigned* m = &lm2[o * 32];
      unsigned acc2 = 0;
#pragma unroll
      for (int q = 0; q < 8; q++) {
        acc2 += __popc(xw[q].x ^ m[q * 4 + 0]);
        acc2 += __popc(xw[q].y ^ m[q * 4 + 1]);
        acc2 += __popc(xw[q].z ^ m[q * 4 + 2]);
        acc2 += __popc(xw[q].w ^ m[q * 4 + 3]);
      }
      int bit = ((int)(1024u - acc2)) > thr2[o];
      val |= bit << (7 - b);                            // MSB-first
    }
    out[c * 65536 + n] = (float)val;
    out[196608 + c * 65536 + n] = (float)val - image[c * 65536 + n];
  }
}

extern "C" void kernel_launch(void* const* d_in, const int* in_sizes, int n_in,
                              void* d_out, int out_size, void* d_ws, size_t ws_size,
                              hipStream_t stream) {
  const float*         image = (const float*)d_in[0];
  const unsigned char* mask0 = (const unsigned char*)d_in[1];
  const int*           thr0  = (const int*)d_in[2];
  const unsigned char* mask1 = (const unsigned char*)d_in[3];
  const int*           thr1  = (const int*)d_in[4];
  const unsigned char* mask2 = (const unsigned char*)d_in[5];
  const int*           thr2  = (const int*)d_in[6];
  char* ws = (char*)d_ws;
  signed char*    cA    = (signed char*)(ws + WS_CA);
  unsigned char*  cB    = (unsigned char*)(ws + WS_CB);
  unsigned*       M2p   = (unsigned*)(ws + WS_M2P);
  int*            carr  = (int*)(ws + WS_CARR);
  unsigned char*  Bf    = (unsigned char*)(ws + WS_BF);
  unsigned*       X2p   = (unsigned*)(ws + WS_X2);
  float* out = (float*)d_out;

  hipLaunchKernelGGL(prep_kernel, dim3(3075), dim3(256), 0, stream,
                     mask0, thr0, mask1, mask2, cA, cB, Bf, M2p);
  hipLaunchKernelGGL(popm_kernel, dim3(1024), dim3(64), 0, stream,
                     Bf, thr1, carr);
  hipLaunchKernelGGL(main_kernel, dim3(1024), dim3(512), 0, stream,
                     cA, cB, Bf, carr, X2p);
  hipLaunchKernelGGL(l2_kernel, dim3(256), dim3(256), 0, stream,
                     (const uint4*)X2p, M2p, thr2, image, out);
}